// Round 21
// baseline (266.717 us; speedup 1.0000x reference)
//
#include <hip/hip_runtime.h>
#include <hip/hip_fp16.h>
#include <hip/hip_fp8.h>

#define RESO 128
#define SH_C 27
#define NFINE (32*32*32)    // scatter cell = 4^3 voxels (low atomic contention)
#define NCOARSE (16*16*16)  // gather cell = 8^3 voxels (staging amortization)
#define CAPB 96             // fine bucket capacity (mean 61, 4.5 sigma)
#define OVF_CAP 16384
#define PACK_ROWS 64        // rows per pack block (6912B LDS), 4 threads/row
#define PACK_PER_G 16       // interleave: 16 pack blocks + 5 scatter blocks per group
#define SCAT_PER_G 5
#define GROUP (PACK_PER_G + SCAT_PER_G)
#define OVF_BLOCKS 64
#define NROWS 729           // 9^3 staged rows per coarse cell
#define QSTEP 2048.0f       // 2^-11 position quantization (range [0,4) -> 13 bits)
#define QINV  (1.0f/2048.0f)

// ---------------- helpers ----------------
__device__ __forceinline__ void point_to_voxel(float px, float py, float pz,
                                               int& lx, int& ly, int& lz,
                                               float& cx, float& cy, float& cz) {
    cx = fminf(fmaxf(px, 0.0f), (float)(RESO - 1));
    cy = fminf(fmaxf(py, 0.0f), (float)(RESO - 1));
    cz = fminf(fmaxf(pz, 0.0f), (float)(RESO - 1));
    lx = min(max((int)floorf(cx), 0), RESO - 2);
    ly = min(max((int)floorf(cy), 0), RESO - 2);
    lz = min(max((int)floorf(cz), 0), RESO - 2);
}

__device__ __forceinline__ int fine_cell_of(int lx, int ly, int lz) {
    return ((lx >> 2) << 10) | ((ly >> 2) << 5) | (lz >> 2);
}

// ---------------- fp8 decode ----------------
#if defined(__has_builtin)
#if __has_builtin(__builtin_amdgcn_cvt_pk_f32_fp8)
#define HAVE_CVT_PK_FP8 1
#endif
#endif

typedef float v2f __attribute__((ext_vector_type(2)));

__device__ __forceinline__ float fp8_to_f32_sw(unsigned int b) {
    const unsigned int s = (b >> 7) & 1u, e = (b >> 3) & 15u, m = b & 7u;
    float v;
    if (e == 0) v = (float)m * 0.001953125f;                       // m * 2^-9
    else        v = __uint_as_float(((e + 120u) << 23) | (m << 20));
    return s ? -v : v;
}

__device__ __forceinline__ void acc4_fp8(unsigned int w, float wt, float* a) {
#ifdef HAVE_CVT_PK_FP8
    const v2f lo = __builtin_amdgcn_cvt_pk_f32_fp8((int)w, false);
    const v2f hi = __builtin_amdgcn_cvt_pk_f32_fp8((int)w, true);
    a[0] = fmaf(wt, lo.x, a[0]);
    a[1] = fmaf(wt, lo.y, a[1]);
    a[2] = fmaf(wt, hi.x, a[2]);
    a[3] = fmaf(wt, hi.y, a[3]);
#else
    a[0] = fmaf(wt, fp8_to_f32_sw(w & 0xff), a[0]);
    a[1] = fmaf(wt, fp8_to_f32_sw((w >> 8) & 0xff), a[1]);
    a[2] = fmaf(wt, fp8_to_f32_sw((w >> 16) & 0xff), a[2]);
    a[3] = fmaf(wt, fp8_to_f32_sw((w >> 24) & 0xff), a[3]);
#endif
}

// accumulate one 32B row (layout: f32 density | 27 fp8 | pad) given its two 16B halves
__device__ __forceinline__ void accum_row(const uint4& q0, const uint4& q1,
                                          float wt, float& accd, float* accs) {
    accd = fmaf(wt, __uint_as_float(q0.x), accd);
    acc4_fp8(q0.y, wt, accs + 0);
    acc4_fp8(q0.z, wt, accs + 4);
    acc4_fp8(q0.w, wt, accs + 8);
    acc4_fp8(q1.x, wt, accs + 12);
    acc4_fp8(q1.y, wt, accs + 16);
    acc4_fp8(q1.z, wt, accs + 20);
    acc4_fp8(q1.w, wt, accs + 24);   // accs[27] = pad -> 0
}

__device__ __forceinline__ void write_out(int orig, float accd, const float* accs,
                                          float* __restrict__ out_d,
                                          float* __restrict__ out_sh) {
    out_d[orig] = accd;                                   // plain cached stores:
    float* __restrict__ o = out_sh + (size_t)orig * SH_C; // L2 merges the 112B run
    #pragma unroll
    for (int c = 0; c < SH_C; ++c) o[c] = accs[c];
}

// ---------------- fused, block-interleaved: pack + fine-bucket-scatter (8B entry) ----------------
__global__ __launch_bounds__(256) void fused_pack_scatter_kernel(
    const float* __restrict__ density, const float* __restrict__ sh,
    uint4* __restrict__ rows, int cap, int gridp,
    const float* __restrict__ pts, int n, int grids,
    int* __restrict__ cnt, int* __restrict__ ovfcnt,
    uint2* __restrict__ bucket, int* __restrict__ ovf)
{
    __shared__ float sv[PACK_ROWS * SH_C];   // 6912 B

    const int bid = blockIdx.x;
    const int g = bid / GROUP, rr = bid % GROUP;

    if (rr < PACK_PER_G) {
        // ---- pack 64 rows, 4 threads per row ----
        const int pid = g * PACK_PER_G + rr;
        if (pid >= gridp) return;
        const int r0 = pid * PACK_ROWS;
        const int nrows = min(PACK_ROWS, cap - r0);
        if (nrows <= 0) return;
        const float* __restrict__ src = sh + (size_t)r0 * SH_C;
        if (nrows == PACK_ROWS) {
            const float4* __restrict__ s4 = (const float4*)src;   // 6912B, 16B-aligned
            float4* d4 = (float4*)sv;
            for (int k = threadIdx.x; k < PACK_ROWS * SH_C / 4; k += 256) d4[k] = s4[k];
        } else {
            for (int k = threadIdx.x; k < nrows * SH_C; k += 256) sv[k] = src[k];
        }
        __syncthreads();
        const int t   = threadIdx.x;
        const int row = t >> 2;           // 0..63
        const int s   = t & 3;            // 8B sub-chunk of the 32B row
        if (row < nrows) {
            const int r = r0 + row;
            const float* __restrict__ sr = sv + row * SH_C;
            union { uint2 u; unsigned char b[8]; float f[2]; } pk;
            if (s == 0) {
                pk.f[0] = density[r];
                #pragma unroll
                for (int c = 0; c < 4; ++c)
                    pk.b[4 + c] = __hip_cvt_float_to_fp8(sr[c], __HIP_SATFINITE, __HIP_E4M3);
            } else {
                const int c0 = s * 8 - 4;          // 4, 12, 20
                #pragma unroll
                for (int c = 0; c < 8; ++c) {
                    const int cc = c0 + c;
                    pk.b[c] = (cc < SH_C)
                        ? __hip_cvt_float_to_fp8(sr[cc], __HIP_SATFINITE, __HIP_E4M3)
                        : (unsigned char)0;
                }
            }
            *(uint2*)((char*)rows + (size_t)r * 32 + s * 8) = pk.u;  // coalesced 8B/thread
        }
    } else {
        // ---- scatter packed {index, local quantized pos} into fine buckets ----
        const int sid = g * SCAT_PER_G + (rr - PACK_PER_G);
        if (sid >= grids) return;
        const int i = sid * 256 + threadIdx.x;
        if (i >= n) return;
        const float px = pts[3*(size_t)i], py = pts[3*(size_t)i+1], pz = pts[3*(size_t)i+2];
        int lx, ly, lz; float cx, cy, cz;
        point_to_voxel(px, py, pz, lx, ly, lz, cx, cy, cz);
        const int cell = fine_cell_of(lx, ly, lz);
        const int slot = atomicAdd(&cnt[cell], 1);
        if (slot < CAPB) {
            const unsigned qx = min((unsigned)__float2int_rn((cx - (float)(lx & ~3)) * QSTEP), 8191u);
            const unsigned qy = min((unsigned)__float2int_rn((cy - (float)(ly & ~3)) * QSTEP), 8191u);
            const unsigned qz = min((unsigned)__float2int_rn((cz - (float)(lz & ~3)) * QSTEP), 8191u);
            const unsigned long long v = (unsigned long long)(unsigned)i
                                       | ((unsigned long long)qx << 21)
                                       | ((unsigned long long)qy << 34)
                                       | ((unsigned long long)qz << 47);
            uint2 e; e.x = (unsigned)v; e.y = (unsigned)(v >> 32);
            bucket[(size_t)cell * CAPB + slot] = e;    // plain 8B store: L2 merges
        } else {
            const int o = atomicAdd(ovfcnt, 1);
            if (o < OVF_CAP) ovf[o] = i;
        }
    }
}

// ---------------- main: one 8^3 coarse cell per 256-thread block;
//                  stages 9^3 rows (split halves for LDS bank spread),
//                  drains its 8 child fine buckets;
//                  first OVF_BLOCKS blocks also drain the overflow list ----------------
__global__ __launch_bounds__(256) void sample_bucket_kernel(
    const uint4* __restrict__ rows,     // [CAP,2] uint4 = 32B row
    const int*   __restrict__ links,    // [128,128,128]
    const float* __restrict__ pts,      // [N,3] original points (overflow path only)
    const uint2* __restrict__ bucket,   // [NFINE, CAPB] packed entries
    const int*   __restrict__ cnt,      // [NFINE]
    const int*   __restrict__ ovf,      // overflow indices
    const int*   __restrict__ ovfcnt,
    float* __restrict__ out_d,          // [N]
    float* __restrict__ out_sh)         // [N,27]
{
    __shared__ int   slk[NROWS];          // 9x9x9 links (2916 B)
    __shared__ uint4 srowA[NROWS];        // first 16B of each row (16B stride -> 8 bank phases)
    __shared__ uint4 srowB[NROWS];        // second 16B of each row
    __shared__ int   soff[9];             // prefix over the 8 fine-bucket counts

    // bijective chunked XCD swizzle: 4096 = 8 * 512
    const int bid = blockIdx.x;
    const int cell = ((bid & 7) << 9) | (bid >> 3);
    const int bx = ((cell >> 8) & 15) << 3;
    const int by = ((cell >> 4) & 15) << 3;
    const int bz = (cell & 15) << 3;
    const int tid = threadIdx.x;

    // stage links (clamped at grid edge; those entries are never used as corners)
    for (int i = tid; i < NROWS; i += 256) {
        const int rx = i / 81, rem = i - rx * 81;
        const int ry = rem / 9, rz = rem - ry * 9;
        const int gx = min(bx + rx, RESO - 1);
        const int gy = min(by + ry, RESO - 1);
        const int gz = min(bz + rz, RESO - 1);
        slk[i] = links[(gx << 14) | (gy << 7) | gz];
    }
    // fine-bucket counts -> prefix (serial, 8 entries)
    if (tid == 0) {
        int acc = 0;
        soff[0] = 0;
        #pragma unroll
        for (int f = 0; f < 8; ++f) {
            const int fx = (bx >> 2) + ((f >> 2) & 1);
            const int fy = (by >> 2) + ((f >> 1) & 1);
            const int fz = (bz >> 2) + (f & 1);
            const int fc = (fx << 10) | (fy << 5) | fz;
            acc += min(cnt[fc], CAPB);
            soff[f + 1] = acc;
        }
    }
    __syncthreads();

    // stage the 729 rows (zero for invalid links): 1458 uint4 gathers, split halves
    for (int i = tid; i < NROWS * 2; i += 256) {
        const int lrow = i >> 1, half = i & 1;
        const int link = slk[lrow];
        uint4 v = make_uint4(0u, 0u, 0u, 0u);
        if (link >= 0) v = rows[(size_t)link * 2 + half];
        if (half) srowB[lrow] = v; else srowA[lrow] = v;
    }
    __syncthreads();

    const int M = soff[8];

    for (int j = tid; j < M; j += 256) {
        // find fine bucket f: soff[f] <= j < soff[f+1]   (8-way, unrolled compare)
        int f = 0;
        #pragma unroll
        for (int t = 1; t < 8; ++t) f += (j >= soff[t]);
        const int fx = (bx >> 2) + ((f >> 2) & 1);
        const int fy = (by >> 2) + ((f >> 1) & 1);
        const int fz = (bz >> 2) + (f & 1);
        const int fc = (fx << 10) | (fy << 5) | fz;

        const uint2 e = bucket[(size_t)fc * CAPB + (j - soff[f])];
        const unsigned long long v = (unsigned long long)e.x
                                   | ((unsigned long long)e.y << 32);
        const int orig = (int)(v & 0x1FFFFFu);
        const float cx = (float)(fx << 2) + (float)((v >> 21) & 0x1FFFu) * QINV;
        const float cy = (float)(fy << 2) + (float)((v >> 34) & 0x1FFFu) * QINV;
        const float cz = (float)(fz << 2) + (float)((v >> 47) & 0x1FFFu) * QINV;

        const int lx = min((int)cx, RESO - 2);
        const int ly = min((int)cy, RESO - 2);
        const int lz = min((int)cz, RESO - 2);

        const float wx = cx - (float)lx;
        const float wy = cy - (float)ly;
        const float wz = cz - (float)lz;
        const int ox = lx - bx, oy = ly - by, oz = lz - bz;   // 0..7

        float accd = 0.0f, accs[28];
        #pragma unroll
        for (int c = 0; c < 28; ++c) accs[c] = 0.0f;

        const int lrow0 = ox * 81 + oy * 9 + oz;
        #pragma unroll
        for (int k = 0; k < 8; ++k) {
            const int dx = (k >> 2) & 1;
            const int dy = (k >> 1) & 1;
            const int dz = k & 1;
            const int lrow = lrow0 + dx * 81 + dy * 9 + dz;
            const float wt = (slk[lrow] >= 0)
                ? (dx ? wx : 1.0f - wx) * (dy ? wy : 1.0f - wy) * (dz ? wz : 1.0f - wz)
                : 0.0f;
            accum_row(srowA[lrow], srowB[lrow], wt, accd, accs);
        }

        write_out(orig, accd, accs, out_d, out_sh);
    }

    // ---- overflow drain (direct gather), first OVF_BLOCKS blocks only ----
    if (bid < OVF_BLOCKS) {
        const int mo = min(*ovfcnt, OVF_CAP);
        for (int i = bid * 256 + tid; i < mo; i += OVF_BLOCKS * 256) {
            const int orig = ovf[i];
            const float px = pts[3*(size_t)orig];
            const float py = pts[3*(size_t)orig + 1];
            const float pz = pts[3*(size_t)orig + 2];
            int lx, ly, lz; float cx, cy, cz;
            point_to_voxel(px, py, pz, lx, ly, lz, cx, cy, cz);
            const float wx = cx - (float)lx, wy = cy - (float)ly, wz = cz - (float)lz;
            float accd = 0.0f, accs[28];
            #pragma unroll
            for (int c = 0; c < 28; ++c) accs[c] = 0.0f;
            const int base = (lx << 14) + (ly << 7) + lz;
            #pragma unroll
            for (int k = 0; k < 8; ++k) {
                const int dx = (k >> 2) & 1, dy = (k >> 1) & 1, dz = k & 1;
                const int idx = links[base + (dx << 14) + (dy << 7) + dz];
                const int safe = idx < 0 ? 0 : idx;
                const float wt = (idx >= 0)
                    ? (dx ? wx : 1.0f - wx) * (dy ? wy : 1.0f - wy) * (dz ? wz : 1.0f - wz)
                    : 0.0f;
                accum_row(rows[(size_t)safe*2], rows[(size_t)safe*2+1], wt, accd, accs);
            }
            write_out(orig, accd, accs, out_d, out_sh);
        }
    }
}

// fallback (round-1 kernel) if ws too small
__global__ __launch_bounds__(256) void sample_direct_kernel(
    const float* __restrict__ density, const float* __restrict__ sh,
    const int* __restrict__ links, const float* __restrict__ points,
    float* __restrict__ out_d, float* __restrict__ out_sh, int n)
{
    int i = blockIdx.x * blockDim.x + threadIdx.x;
    if (i >= n) return;
    int lx, ly, lz; float cx, cy, cz;
    point_to_voxel(points[3*(size_t)i], points[3*(size_t)i+1], points[3*(size_t)i+2],
                   lx, ly, lz, cx, cy, cz);
    const float wx = cx - (float)lx, wy = cy - (float)ly, wz = cz - (float)lz;
    float accd = 0.0f, accs[SH_C];
    #pragma unroll
    for (int c = 0; c < SH_C; ++c) accs[c] = 0.0f;
    const int base = lx * (RESO * RESO) + ly * RESO + lz;
    #pragma unroll
    for (int k = 0; k < 8; ++k) {
        const int dx = (k >> 2) & 1, dy = (k >> 1) & 1, dz = k & 1;
        const int idx = links[base + dx * (RESO * RESO) + dy * RESO + dz];
        if (idx >= 0) {
            const float wt = (dx ? wx : 1.0f - wx) * (dy ? wy : 1.0f - wy) * (dz ? wz : 1.0f - wz);
            accd = fmaf(wt, density[idx], accd);
            const float* row = sh + (size_t)idx * SH_C;
            #pragma unroll
            for (int c = 0; c < SH_C; ++c) accs[c] = fmaf(wt, row[c], accs[c]);
        }
    }
    out_d[i] = accd;
    float* o = out_sh + (size_t)i * SH_C;
    #pragma unroll
    for (int c = 0; c < SH_C; ++c) o[c] = accs[c];
}

extern "C" void kernel_launch(void* const* d_in, const int* in_sizes, int n_in,
                              void* d_out, int out_size, void* d_ws, size_t ws_size,
                              hipStream_t stream) {
    const float* density = (const float*)d_in[0];
    const float* sh      = (const float*)d_in[1];
    const int*   links   = (const int*)d_in[2];
    const float* points  = (const float*)d_in[3];

    const int cap = in_sizes[0];
    const int n   = in_sizes[3] / 3;

    float* out_d  = (float*)d_out;
    float* out_sh = out_d + n;

    const int gridp = (cap + PACK_ROWS - 1) / PACK_ROWS;
    const int grids = (n + 255) / 256;
    const int ngroups = max((gridp + PACK_PER_G - 1) / PACK_PER_G,
                            (grids + SCAT_PER_G - 1) / SCAT_PER_G);

    // ws layout: cnt[NFINE] | ovfcnt | bucket[NFINE*CAPB] uint2 | ovf[OVF_CAP] int | rows uint4
    const size_t cnt_bytes  = (size_t)NFINE * sizeof(int);
    const size_t ovfc_off   = cnt_bytes;                       // 4 bytes
    const size_t bucket_off = (cnt_bytes + 256 + 255) & ~(size_t)255;
    const size_t ovf_off    = (bucket_off + (size_t)NFINE * CAPB * sizeof(uint2) + 255) & ~(size_t)255;
    const size_t rows_off   = (ovf_off + (size_t)OVF_CAP * sizeof(int) + 255) & ~(size_t)255;
    const size_t need       = rows_off + (size_t)cap * 32;

    if (ws_size >= need && n < (1 << 21)) {
        int*    cnt    = (int*)d_ws;
        int*    ovfcnt = (int*)((char*)d_ws + ovfc_off);
        uint2*  bucket = (uint2*)((char*)d_ws + bucket_off);
        int*    ovf    = (int*)((char*)d_ws + ovf_off);
        uint4*  rows   = (uint4*)((char*)d_ws + rows_off);

        hipMemsetAsync(d_ws, 0, cnt_bytes + 256, stream);
        fused_pack_scatter_kernel<<<ngroups * GROUP, 256, 0, stream>>>(
            density, sh, rows, cap, gridp, points, n, grids, cnt, ovfcnt, bucket, ovf);
        sample_bucket_kernel<<<NCOARSE, 256, 0, stream>>>(rows, links, points, bucket, cnt,
                                                          ovf, ovfcnt, out_d, out_sh);
    } else {
        sample_direct_kernel<<<(n + 255) / 256, 256, 0, stream>>>(
            density, sh, links, points, out_d, out_sh, n);
    }
}

// Round 22
// 263.141 us; speedup vs baseline: 1.0136x; 1.0136x over previous
//
#include <hip/hip_runtime.h>
#include <hip/hip_fp16.h>
#include <hip/hip_fp8.h>

#define RESO 128
#define SH_C 27
#define NFINE (32*32*32)    // scatter cell = 4^3 voxels (low atomic contention)
#define NCOARSE (16*16*16)  // gather cell = 8^3 voxels (staging amortization)
#define CAPB 96             // fine bucket capacity (mean 61, 4.5 sigma)
#define OVF_CAP 16384
#define PACK_ROWS 64        // rows per pack block (6912B LDS), 4 threads/row
#define PACK_PER_G 16       // interleave: 16 pack blocks + 5 scatter blocks per group
#define SCAT_PER_G 5
#define GROUP (PACK_PER_G + SCAT_PER_G)
#define OVF_BLOCKS 64
#define NROWS 729           // 9^3 staged rows per coarse cell
#define QSTEP 2048.0f       // 2^-11 position quantization (range [0,4) -> 13 bits)
#define QINV  (1.0f/2048.0f)

// ---------------- helpers ----------------
__device__ __forceinline__ void point_to_voxel(float px, float py, float pz,
                                               int& lx, int& ly, int& lz,
                                               float& cx, float& cy, float& cz) {
    cx = fminf(fmaxf(px, 0.0f), (float)(RESO - 1));
    cy = fminf(fmaxf(py, 0.0f), (float)(RESO - 1));
    cz = fminf(fmaxf(pz, 0.0f), (float)(RESO - 1));
    lx = min(max((int)floorf(cx), 0), RESO - 2);
    ly = min(max((int)floorf(cy), 0), RESO - 2);
    lz = min(max((int)floorf(cz), 0), RESO - 2);
}

__device__ __forceinline__ int fine_cell_of(int lx, int ly, int lz) {
    return ((lx >> 2) << 10) | ((ly >> 2) << 5) | (lz >> 2);
}

// ---------------- fp8 decode ----------------
#if defined(__has_builtin)
#if __has_builtin(__builtin_amdgcn_cvt_pk_f32_fp8)
#define HAVE_CVT_PK_FP8 1
#endif
#endif

typedef float v2f __attribute__((ext_vector_type(2)));

__device__ __forceinline__ float fp8_to_f32_sw(unsigned int b) {
    const unsigned int s = (b >> 7) & 1u, e = (b >> 3) & 15u, m = b & 7u;
    float v;
    if (e == 0) v = (float)m * 0.001953125f;                       // m * 2^-9
    else        v = __uint_as_float(((e + 120u) << 23) | (m << 20));
    return s ? -v : v;
}

__device__ __forceinline__ void acc4_fp8(unsigned int w, float wt, float* a) {
#ifdef HAVE_CVT_PK_FP8
    const v2f lo = __builtin_amdgcn_cvt_pk_f32_fp8((int)w, false);
    const v2f hi = __builtin_amdgcn_cvt_pk_f32_fp8((int)w, true);
    a[0] = fmaf(wt, lo.x, a[0]);
    a[1] = fmaf(wt, lo.y, a[1]);
    a[2] = fmaf(wt, hi.x, a[2]);
    a[3] = fmaf(wt, hi.y, a[3]);
#else
    a[0] = fmaf(wt, fp8_to_f32_sw(w & 0xff), a[0]);
    a[1] = fmaf(wt, fp8_to_f32_sw((w >> 8) & 0xff), a[1]);
    a[2] = fmaf(wt, fp8_to_f32_sw((w >> 16) & 0xff), a[2]);
    a[3] = fmaf(wt, fp8_to_f32_sw((w >> 24) & 0xff), a[3]);
#endif
}

// accumulate one 32B row (layout: f32 density | 27 fp8 | pad)
__device__ __forceinline__ void accum_row(const uint4& q0, const uint4& q1,
                                          float wt, float& accd, float* accs) {
    accd = fmaf(wt, __uint_as_float(q0.x), accd);
    acc4_fp8(q0.y, wt, accs + 0);
    acc4_fp8(q0.z, wt, accs + 4);
    acc4_fp8(q0.w, wt, accs + 8);
    acc4_fp8(q1.x, wt, accs + 12);
    acc4_fp8(q1.y, wt, accs + 16);
    acc4_fp8(q1.z, wt, accs + 20);
    acc4_fp8(q1.w, wt, accs + 24);   // accs[27] = pad -> 0
}

__device__ __forceinline__ void write_out(int orig, float accd, const float* accs,
                                          float* __restrict__ out_d,
                                          float* __restrict__ out_sh) {
    out_d[orig] = accd;                                   // plain cached stores:
    float* __restrict__ o = out_sh + (size_t)orig * SH_C; // L2 merges the 112B run
    #pragma unroll
    for (int c = 0; c < SH_C; ++c) o[c] = accs[c];
}

// ---------------- fused, block-interleaved: pack + fine-bucket-scatter (8B entry) ----------------
__global__ __launch_bounds__(256) void fused_pack_scatter_kernel(
    const float* __restrict__ density, const float* __restrict__ sh,
    uint4* __restrict__ rows, int cap, int gridp,
    const float* __restrict__ pts, int n, int grids,
    int* __restrict__ cnt, int* __restrict__ ovfcnt,
    uint2* __restrict__ bucket, int* __restrict__ ovf)
{
    __shared__ float sv[PACK_ROWS * SH_C];   // 6912 B

    const int bid = blockIdx.x;
    const int g = bid / GROUP, rr = bid % GROUP;

    if (rr < PACK_PER_G) {
        // ---- pack 64 rows, 4 threads per row ----
        const int pid = g * PACK_PER_G + rr;
        if (pid >= gridp) return;
        const int r0 = pid * PACK_ROWS;
        const int nrows = min(PACK_ROWS, cap - r0);
        if (nrows <= 0) return;
        const float* __restrict__ src = sh + (size_t)r0 * SH_C;
        if (nrows == PACK_ROWS) {
            const float4* __restrict__ s4 = (const float4*)src;   // 6912B, 16B-aligned
            float4* d4 = (float4*)sv;
            for (int k = threadIdx.x; k < PACK_ROWS * SH_C / 4; k += 256) d4[k] = s4[k];
        } else {
            for (int k = threadIdx.x; k < nrows * SH_C; k += 256) sv[k] = src[k];
        }
        __syncthreads();
        const int t   = threadIdx.x;
        const int row = t >> 2;           // 0..63
        const int s   = t & 3;            // 8B sub-chunk of the 32B row
        if (row < nrows) {
            const int r = r0 + row;
            const float* __restrict__ sr = sv + row * SH_C;
            union { uint2 u; unsigned char b[8]; float f[2]; } pk;
            if (s == 0) {
                pk.f[0] = density[r];
                #pragma unroll
                for (int c = 0; c < 4; ++c)
                    pk.b[4 + c] = __hip_cvt_float_to_fp8(sr[c], __HIP_SATFINITE, __HIP_E4M3);
            } else {
                const int c0 = s * 8 - 4;          // 4, 12, 20
                #pragma unroll
                for (int c = 0; c < 8; ++c) {
                    const int cc = c0 + c;
                    pk.b[c] = (cc < SH_C)
                        ? __hip_cvt_float_to_fp8(sr[cc], __HIP_SATFINITE, __HIP_E4M3)
                        : (unsigned char)0;
                }
            }
            *(uint2*)((char*)rows + (size_t)r * 32 + s * 8) = pk.u;  // coalesced 8B/thread
        }
    } else {
        // ---- scatter packed {index, local quantized pos} into fine buckets ----
        const int sid = g * SCAT_PER_G + (rr - PACK_PER_G);
        if (sid >= grids) return;
        const int i = sid * 256 + threadIdx.x;
        if (i >= n) return;
        const float px = pts[3*(size_t)i], py = pts[3*(size_t)i+1], pz = pts[3*(size_t)i+2];
        int lx, ly, lz; float cx, cy, cz;
        point_to_voxel(px, py, pz, lx, ly, lz, cx, cy, cz);
        const int cell = fine_cell_of(lx, ly, lz);
        const int slot = atomicAdd(&cnt[cell], 1);
        if (slot < CAPB) {
            const unsigned qx = min((unsigned)__float2int_rn((cx - (float)(lx & ~3)) * QSTEP), 8191u);
            const unsigned qy = min((unsigned)__float2int_rn((cy - (float)(ly & ~3)) * QSTEP), 8191u);
            const unsigned qz = min((unsigned)__float2int_rn((cz - (float)(lz & ~3)) * QSTEP), 8191u);
            const unsigned long long v = (unsigned long long)(unsigned)i
                                       | ((unsigned long long)qx << 21)
                                       | ((unsigned long long)qy << 34)
                                       | ((unsigned long long)qz << 47);
            uint2 e; e.x = (unsigned)v; e.y = (unsigned)(v >> 32);
            bucket[(size_t)cell * CAPB + slot] = e;    // plain 8B store: L2 merges
        } else {
            const int o = atomicAdd(ovfcnt, 1);
            if (o < OVF_CAP) ovf[o] = i;
        }
    }
}

// ---------------- main: one 8^3 coarse cell per 256-thread block;
//                  stages 9^3 rows, drains its 8 child fine buckets;
//                  first OVF_BLOCKS blocks also drain the overflow list ----------------
__global__ __launch_bounds__(256) void sample_bucket_kernel(
    const uint4* __restrict__ rows,     // [CAP,2] uint4 = 32B row
    const int*   __restrict__ links,    // [128,128,128]
    const float* __restrict__ pts,      // [N,3] original points (overflow path only)
    const uint2* __restrict__ bucket,   // [NFINE, CAPB] packed entries
    const int*   __restrict__ cnt,      // [NFINE]
    const int*   __restrict__ ovf,      // overflow indices
    const int*   __restrict__ ovfcnt,
    float* __restrict__ out_d,          // [N]
    float* __restrict__ out_sh)         // [N,27]
{
    __shared__ int   slk[NROWS];          // 9x9x9 links (2916 B)
    __shared__ uint4 srow[NROWS * 2];     // 9x9x9 rows, 32B each (23328 B)
    __shared__ int   soff[9];             // prefix over the 8 fine-bucket counts

    // bijective chunked XCD swizzle: 4096 = 8 * 512
    const int bid = blockIdx.x;
    const int cell = ((bid & 7) << 9) | (bid >> 3);
    const int bx = ((cell >> 8) & 15) << 3;
    const int by = ((cell >> 4) & 15) << 3;
    const int bz = (cell & 15) << 3;
    const int tid = threadIdx.x;

    // stage links (clamped at grid edge; those entries are never used as corners)
    for (int i = tid; i < NROWS; i += 256) {
        const int rx = i / 81, rem = i - rx * 81;
        const int ry = rem / 9, rz = rem - ry * 9;
        const int gx = min(bx + rx, RESO - 1);
        const int gy = min(by + ry, RESO - 1);
        const int gz = min(bz + rz, RESO - 1);
        slk[i] = links[(gx << 14) | (gy << 7) | gz];
    }
    // fine-bucket counts -> prefix (serial, 8 entries)
    if (tid == 0) {
        int acc = 0;
        soff[0] = 0;
        #pragma unroll
        for (int f = 0; f < 8; ++f) {
            const int fx = (bx >> 2) + ((f >> 2) & 1);
            const int fy = (by >> 2) + ((f >> 1) & 1);
            const int fz = (bz >> 2) + (f & 1);
            const int fc = (fx << 10) | (fy << 5) | fz;
            acc += min(cnt[fc], CAPB);
            soff[f + 1] = acc;
        }
    }
    __syncthreads();

    // stage the 729 rows (zero for invalid links): 1458 uint4 gathers
    for (int i = tid; i < NROWS * 2; i += 256) {
        const int lrow = i >> 1, half = i & 1;
        const int link = slk[lrow];
        uint4 v = make_uint4(0u, 0u, 0u, 0u);
        if (link >= 0) v = rows[(size_t)link * 2 + half];
        srow[i] = v;
    }
    __syncthreads();

    const int M = soff[8];

    for (int j = tid; j < M; j += 256) {
        // find fine bucket f: soff[f] <= j < soff[f+1]   (8-way, unrolled compare)
        int f = 0;
        #pragma unroll
        for (int t = 1; t < 8; ++t) f += (j >= soff[t]);
        const int fx = (bx >> 2) + ((f >> 2) & 1);
        const int fy = (by >> 2) + ((f >> 1) & 1);
        const int fz = (bz >> 2) + (f & 1);
        const int fc = (fx << 10) | (fy << 5) | fz;

        const uint2 e = bucket[(size_t)fc * CAPB + (j - soff[f])];
        const unsigned long long v = (unsigned long long)e.x
                                   | ((unsigned long long)e.y << 32);
        const int orig = (int)(v & 0x1FFFFFu);
        const float cx = (float)(fx << 2) + (float)((v >> 21) & 0x1FFFu) * QINV;
        const float cy = (float)(fy << 2) + (float)((v >> 34) & 0x1FFFu) * QINV;
        const float cz = (float)(fz << 2) + (float)((v >> 47) & 0x1FFFu) * QINV;

        const int lx = min((int)cx, RESO - 2);
        const int ly = min((int)cy, RESO - 2);
        const int lz = min((int)cz, RESO - 2);

        const float wx = cx - (float)lx;
        const float wy = cy - (float)ly;
        const float wz = cz - (float)lz;
        const int ox = lx - bx, oy = ly - by, oz = lz - bz;   // 0..7

        float accd = 0.0f, accs[28];
        #pragma unroll
        for (int c = 0; c < 28; ++c) accs[c] = 0.0f;

        const int lrow0 = ox * 81 + oy * 9 + oz;
        #pragma unroll
        for (int k = 0; k < 8; ++k) {
            const int dx = (k >> 2) & 1;
            const int dy = (k >> 1) & 1;
            const int dz = k & 1;
            const int lrow = lrow0 + dx * 81 + dy * 9 + dz;
            const float wt = (slk[lrow] >= 0)
                ? (dx ? wx : 1.0f - wx) * (dy ? wy : 1.0f - wy) * (dz ? wz : 1.0f - wz)
                : 0.0f;
            accum_row(srow[lrow * 2], srow[lrow * 2 + 1], wt, accd, accs);
        }

        write_out(orig, accd, accs, out_d, out_sh);
    }

    // ---- overflow drain (direct gather), first OVF_BLOCKS blocks only ----
    if (bid < OVF_BLOCKS) {
        const int mo = min(*ovfcnt, OVF_CAP);
        for (int i = bid * 256 + tid; i < mo; i += OVF_BLOCKS * 256) {
            const int orig = ovf[i];
            const float px = pts[3*(size_t)orig];
            const float py = pts[3*(size_t)orig + 1];
            const float pz = pts[3*(size_t)orig + 2];
            int lx, ly, lz; float cx, cy, cz;
            point_to_voxel(px, py, pz, lx, ly, lz, cx, cy, cz);
            const float wx = cx - (float)lx, wy = cy - (float)ly, wz = cz - (float)lz;
            float accd = 0.0f, accs[28];
            #pragma unroll
            for (int c = 0; c < 28; ++c) accs[c] = 0.0f;
            const int base = (lx << 14) + (ly << 7) + lz;
            #pragma unroll
            for (int k = 0; k < 8; ++k) {
                const int dx = (k >> 2) & 1, dy = (k >> 1) & 1, dz = k & 1;
                const int idx = links[base + (dx << 14) + (dy << 7) + dz];
                const int safe = idx < 0 ? 0 : idx;
                const float wt = (idx >= 0)
                    ? (dx ? wx : 1.0f - wx) * (dy ? wy : 1.0f - wy) * (dz ? wz : 1.0f - wz)
                    : 0.0f;
                accum_row(rows[(size_t)safe*2], rows[(size_t)safe*2+1], wt, accd, accs);
            }
            write_out(orig, accd, accs, out_d, out_sh);
        }
    }
}

// fallback (round-1 kernel) if ws too small
__global__ __launch_bounds__(256) void sample_direct_kernel(
    const float* __restrict__ density, const float* __restrict__ sh,
    const int* __restrict__ links, const float* __restrict__ points,
    float* __restrict__ out_d, float* __restrict__ out_sh, int n)
{
    int i = blockIdx.x * blockDim.x + threadIdx.x;
    if (i >= n) return;
    int lx, ly, lz; float cx, cy, cz;
    point_to_voxel(points[3*(size_t)i], points[3*(size_t)i+1], points[3*(size_t)i+2],
                   lx, ly, lz, cx, cy, cz);
    const float wx = cx - (float)lx, wy = cy - (float)ly, wz = cz - (float)lz;
    float accd = 0.0f, accs[SH_C];
    #pragma unroll
    for (int c = 0; c < SH_C; ++c) accs[c] = 0.0f;
    const int base = lx * (RESO * RESO) + ly * RESO + lz;
    #pragma unroll
    for (int k = 0; k < 8; ++k) {
        const int dx = (k >> 2) & 1, dy = (k >> 1) & 1, dz = k & 1;
        const int idx = links[base + dx * (RESO * RESO) + dy * RESO + dz];
        if (idx >= 0) {
            const float wt = (dx ? wx : 1.0f - wx) * (dy ? wy : 1.0f - wy) * (dz ? wz : 1.0f - wz);
            accd = fmaf(wt, density[idx], accd);
            const float* row = sh + (size_t)idx * SH_C;
            #pragma unroll
            for (int c = 0; c < SH_C; ++c) accs[c] = fmaf(wt, row[c], accs[c]);
        }
    }
    out_d[i] = accd;
    float* o = out_sh + (size_t)i * SH_C;
    #pragma unroll
    for (int c = 0; c < SH_C; ++c) o[c] = accs[c];
}

extern "C" void kernel_launch(void* const* d_in, const int* in_sizes, int n_in,
                              void* d_out, int out_size, void* d_ws, size_t ws_size,
                              hipStream_t stream) {
    const float* density = (const float*)d_in[0];
    const float* sh      = (const float*)d_in[1];
    const int*   links   = (const int*)d_in[2];
    const float* points  = (const float*)d_in[3];

    const int cap = in_sizes[0];
    const int n   = in_sizes[3] / 3;

    float* out_d  = (float*)d_out;
    float* out_sh = out_d + n;

    const int gridp = (cap + PACK_ROWS - 1) / PACK_ROWS;
    const int grids = (n + 255) / 256;
    const int ngroups = max((gridp + PACK_PER_G - 1) / PACK_PER_G,
                            (grids + SCAT_PER_G - 1) / SCAT_PER_G);

    // ws layout: cnt[NFINE] | ovfcnt | bucket[NFINE*CAPB] uint2 | ovf[OVF_CAP] int | rows uint4
    const size_t cnt_bytes  = (size_t)NFINE * sizeof(int);
    const size_t ovfc_off   = cnt_bytes;                       // 4 bytes
    const size_t bucket_off = (cnt_bytes + 256 + 255) & ~(size_t)255;
    const size_t ovf_off    = (bucket_off + (size_t)NFINE * CAPB * sizeof(uint2) + 255) & ~(size_t)255;
    const size_t rows_off   = (ovf_off + (size_t)OVF_CAP * sizeof(int) + 255) & ~(size_t)255;
    const size_t need       = rows_off + (size_t)cap * 32;

    if (ws_size >= need && n < (1 << 21)) {
        int*    cnt    = (int*)d_ws;
        int*    ovfcnt = (int*)((char*)d_ws + ovfc_off);
        uint2*  bucket = (uint2*)((char*)d_ws + bucket_off);
        int*    ovf    = (int*)((char*)d_ws + ovf_off);
        uint4*  rows   = (uint4*)((char*)d_ws + rows_off);

        hipMemsetAsync(d_ws, 0, cnt_bytes + 256, stream);
        fused_pack_scatter_kernel<<<ngroups * GROUP, 256, 0, stream>>>(
            density, sh, rows, cap, gridp, points, n, grids, cnt, ovfcnt, bucket, ovf);
        sample_bucket_kernel<<<NCOARSE, 256, 0, stream>>>(rows, links, points, bucket, cnt,
                                                          ovf, ovfcnt, out_d, out_sh);
    } else {
        sample_direct_kernel<<<(n + 255) / 256, 256, 0, stream>>>(
            density, sh, links, points, out_d, out_sh, n);
    }
}